// Round 5
// baseline (259.906 us; speedup 1.0000x reference)
//
#include <hip/hip_runtime.h>
#include <hip/hip_fp16.h>

#define N_PTS 100000
#define MU_F  100.0f

typedef unsigned int uint;
typedef _Float16 h2 __attribute__((ext_vector_type(2)));
typedef float f2 __attribute__((ext_vector_type(2)));

#define E_SCALE 16384.0f
#define E_SCALE_INV (1.0f / 16384.0f)

static __device__ inline h2 h2pack(float a, float b) {
    return __builtin_bit_cast(h2, __builtin_amdgcn_cvt_pkrtz(a, b));
}
static __device__ inline float fdot2f(h2 a, h2 b, float c) {
    return __builtin_amdgcn_fdot2(a, b, c, false);
}
static __device__ inline h2 h2fma(h2 a, h2 b, h2 c) {
#if __has_builtin(__builtin_elementwise_fma)
    return __builtin_elementwise_fma(a, b, c);
#else
    return a * b + c;
#endif
}
static __device__ inline h2 h2max(h2 a, h2 b) {
#if __has_builtin(__builtin_elementwise_max)
    return __builtin_elementwise_max(a, b);
#else
    h2 r;
    r.x = a.x > b.x ? a.x : b.x;
    r.y = a.y > b.y ? a.y : b.y;
    return r;
#endif
}
static __device__ inline f2 f2max(f2 a, f2 b) {
#if __has_builtin(__builtin_elementwise_max)
    return __builtin_elementwise_max(a, b);    // v_pk_max_f32
#else
    f2 r;
    r.x = fmaxf(a.x, b.x);
    r.y = fmaxf(a.y, b.y);
    return r;
#endif
}

#define ENC_BLKS 256
#define TR_BLKS  1563            // ceil(100000/64), appended to K2's grid
#define S_BLKS   1024
#define NPAIRS   (N_PTS / 2)     // 50000
#define S_CH     ((NPAIRS + S_BLKS - 1) / S_BLKS)   // 49
#define M_BLKS   2048
#define M_CH     ((NPAIRS + M_BLKS - 1) / M_BLKS)   // 25

// ---------------------------------------------------------------------------
// K1: encode only. enc[row] = x . encW[row,:] + encB[row]
// ---------------------------------------------------------------------------
__global__ __launch_bounds__(256) void k_prep(const float* __restrict__ x,
                                              const float* __restrict__ encW,
                                              const float* __restrict__ encB,
                                              float* __restrict__ enc) {
    int b = blockIdx.x;
    int row = b & 31;
    int chunk = b >> 5;              // 0..7
    const int CH = N_PTS / 8;        // 12500
    int base = chunk * CH;
    const float4* W4 = reinterpret_cast<const float4*>(encW + (size_t)row * N_PTS + base);
    const float4* x4 = reinterpret_cast<const float4*>(x + base);
    const int nv = CH / 4;           // 3125
    float acc = 0.f;
    for (int idx = threadIdx.x; idx < nv; idx += 256) {
        float4 w = W4[idx];
        float4 xv = x4[idx];
        acc += w.x * xv.x + w.y * xv.y + w.z * xv.z + w.w * xv.w;
    }
    #pragma unroll
    for (int off = 32; off > 0; off >>= 1) acc += __shfl_down(acc, off);
    __shared__ float sred[4];
    int wid = threadIdx.x >> 6;
    if ((threadIdx.x & 63) == 0) sred[wid] = acc;
    __syncthreads();
    if (threadIdx.x == 0) {
        float s = sred[0] + sred[1] + sred[2] + sred[3];
        if (chunk == 0) s += encB[row];
        atomicAdd(enc + row, s);
    }
}

// ---------------------------------------------------------------------------
// K_tab (1 block): build invFG[512] (f32) and invHLG[256] (packed h2) ONCE.
// Round-4 post-mortem: per-block build_invF (uncoalesced 64KB bw_w read)
// was a ~15us/round TA-bound prologue in BOTH hot kernels. Precompute once;
// hot kernels load 1-2KB coalesced tables instead.
// invF[c*32+i] = 1/(sigmoid(enc.bw_w[i*16+c]+b)*MU/60)^2
// ---------------------------------------------------------------------------
__global__ __launch_bounds__(256) void k_tab(const float* __restrict__ enc_g,
                                             const float* __restrict__ bw_w,
                                             const float* __restrict__ bw_b,
                                             float* __restrict__ invFG,
                                             h2* __restrict__ invHLG) {
    __shared__ float encL[32];
    __shared__ float invF[512];
    if (threadIdx.x < 32) encL[threadIdx.x] = enc_g[threadIdx.x];
    __syncthreads();
    for (int r = threadIdx.x; r < 512; r += 256) {
        int i = r >> 4, c = r & 15;
        const float4* wr4 = reinterpret_cast<const float4*>(bw_w + (size_t)r * 32);
        float z = bw_b[r];
        #pragma unroll
        for (int p4 = 0; p4 < 8; ++p4) {    // float4: wave covers 8KB contiguous
            float4 wv = wr4[p4];
            z = fmaf(encL[4 * p4 + 0], wv.x, z);
            z = fmaf(encL[4 * p4 + 1], wv.y, z);
            z = fmaf(encL[4 * p4 + 2], wv.z, z);
            z = fmaf(encL[4 * p4 + 3], wv.w, z);
        }
        float s = 1.f / (1.f + __expf(-z));
        float wmu = s * (MU_F / 60.0f);
        float iv = 1.f / (wmu * wmu);
        invF[c * 32 + i] = iv;
        invFG[c * 32 + i] = iv;
    }
    __syncthreads();
    {
        int t = threadIdx.x;             // 0..255 == 16c x 4q x 4tt
        int c = t >> 4, q = (t >> 2) & 3, tt = t & 3;
        int i0 = q * 8 + 2 * tt;
        invHLG[t] = h2pack(fminf(invF[c * 32 + i0], 6.0e4f),
                           fminf(invF[c * 32 + i0 + 1], 6.0e4f));
    }
}

// ---------------------------------------------------------------------------
// K2: blocks [0,1024): S partials, natural order, ILP-4 inner.
//     Prologue is now a coalesced 2KB invFG load (no build_invF).
//     blocks [1024,2587): dec [32,N] f32 -> decT [N,32] fp16 transpose.
// ---------------------------------------------------------------------------
__global__ __launch_bounds__(256, 8) void k_S(const float* __restrict__ invFG,
                                              const float* __restrict__ nd,
                                              const int* __restrict__ labels,
                                              float* __restrict__ S,
                                              float* __restrict__ S_part,
                                              const float* __restrict__ dec,
                                              __half* __restrict__ decT) {
    int b = blockIdx.x;
    if (b >= S_BLKS) {
        // ----- transpose dec [32,N] f32 -> decT [N,32] fp16 (64B rows)
        __shared__ float tile[32][65];
        int j0 = (b - S_BLKS) * 64;
        int col = threadIdx.x & 63;
        int r0 = threadIdx.x >> 6;       // 0..3
        #pragma unroll
        for (int it = 0; it < 8; ++it) {
            int row = it * 4 + r0;
            int j = j0 + col;
            float v = (j < N_PTS) ? dec[(size_t)row * N_PTS + j] : 0.f;
            tile[row][col] = v;
        }
        __syncthreads();
        #pragma unroll
        for (int it = 0; it < 4; ++it) {
            int idx = it * 256 + threadIdx.x;
            int j = idx >> 4;            // 0..63
            int p = idx & 15;            // i-pair
            int jj = j0 + j;
            if (jj < N_PTS) {
                __half2 h = __halves2half2(__float2half(tile[2 * p][j]),
                                           __float2half(tile[2 * p + 1][j]));
                *reinterpret_cast<__half2*>(decT + (size_t)jj * 32 + 2 * p) = h;
            }
        }
        return;
    }

    __shared__ float invF[512];
    __shared__ float Sloc[1024];
    if (threadIdx.x < 128)               // 2KB coalesced table load
        reinterpret_cast<float4*>(invF)[threadIdx.x] =
            reinterpret_cast<const float4*>(invFG)[threadIdx.x];
    for (int t = threadIdx.x; t < 1024; t += 256) Sloc[t] = 0.f;
    __syncthreads();

    int lane = threadIdx.x & 63;
    int kk = lane & 31;
    int jh = lane >> 5;
    int w = threadIdx.x >> 6;            // wave 0..3
    int start = b * S_CH;
    int pend = min(start + S_CH, NPAIRS);
    int p = start + w;

    f2 acc2[16];
    #pragma unroll
    for (int t = 0; t < 16; ++t) { acc2[t].x = 0.f; acc2[t].y = 0.f; }

    if (p < pend) {
        // invalid pairs get d=1e15 -> w = relu(1 - 1e30*inv) == 0 exactly.
        auto ld4 = [&](int pbase, float* d, int* cc) {
            #pragma unroll
            for (int u = 0; u < 4; ++u) {
                int pc = pbase + 4 * u;
                int pcl = min(pc, NPAIRS - 1);
                int j = 2 * pcl + jh;
                float dv = __builtin_nontemporal_load(&nd[(size_t)j * 32 + kk]);
                cc[u] = labels[j];
                d[u] = (pc < pend) ? dv : 1.0e15f;
            }
        };
        float dA[4], dB[4]; int cA[4], cB[4];
        ld4(p, dA, cA);
        f2 onev; onev.x = 1.f; onev.y = 1.f;
        f2 zero2f; zero2f.x = 0.f; zero2f.y = 0.f;
        while (p < pend) {
            ld4(p + 16, dB, cB);                 // prefetch next batch
            __builtin_amdgcn_sched_barrier(0);
            f2 md[4];
            const float4* ivp[4];
            #pragma unroll
            for (int u = 0; u < 4; ++u) {
                float d2 = dA[u] * dA[u];
                md[u].x = -d2; md[u].y = -d2;
                ivp[u] = reinterpret_cast<const float4*>(&invF[cA[u] * 32]);
            }
            #pragma unroll
            for (int t4 = 0; t4 < 8; ++t4) {
                #pragma unroll
                for (int u = 0; u < 4; ++u) {
                    float4 iv = ivp[u][t4];      // ds_read_b128 (bcast/half-wave)
                    f2 i01; i01.x = iv.x; i01.y = iv.y;
                    f2 i23; i23.x = iv.z; i23.y = iv.w;
                    acc2[2 * t4]     += f2max(md[u] * i01 + onev, zero2f);
                    acc2[2 * t4 + 1] += f2max(md[u] * i23 + onev, zero2f);
                }
            }
            #pragma unroll
            for (int u = 0; u < 4; ++u) { dA[u] = dB[u]; cA[u] = cB[u]; }
            p += 16;
        }
    }
    #pragma unroll
    for (int t = 0; t < 16; ++t) {
        acc2[t].x += __shfl_xor(acc2[t].x, 32);
        acc2[t].y += __shfl_xor(acc2[t].y, 32);
    }
    if (jh == 0) {
        #pragma unroll
        for (int t = 0; t < 16; ++t) {
            atomicAdd(&Sloc[(2 * t) * 32 + kk], acc2[t].x);
            atomicAdd(&Sloc[(2 * t + 1) * 32 + kk], acc2[t].y);
        }
    }
    __syncthreads();
    if (S_part) {
        for (int t = threadIdx.x; t < 1024; t += 256)
            S_part[(size_t)b * 1024 + t] = Sloc[t];
    } else {
        for (int t = threadIdx.x; t < 1024; t += 256) {
            float v = Sloc[t];
            if (v != 0.f) atomicAdd(&S[t], v);
        }
    }
}

// ---------------------------------------------------------------------------
// K3: reduce S_part (1024 x 1024) into S (pre-zeroed). grid 64 x 1024.
// ---------------------------------------------------------------------------
__global__ __launch_bounds__(1024) void k_S_reduce(const float* __restrict__ S_part,
                                                   float* __restrict__ S) {
    int g = blockIdx.x;                  // 0..63
    int t = threadIdx.x;                 // 0..1023
    float s = 0.f;
    #pragma unroll
    for (int u = 0; u < 16; ++u)
        s += S_part[(size_t)(g * 16 + u) * 1024 + t];
    atomicAdd(&S[t], s);
}

// ---------------------------------------------------------------------------
// K_elf (1 block): build pre-packed fp16 E tables ONCE (k_main loses its
// divides, ELf LDS and table builds entirely).
// EhG_A[lane*4+tt] = pack(ELf[i0*32+R], ELf[(i0+1)*32+R]),  i0 = q*8+2tt,
// lane = R*4+q decomposed as R=lane>>2, q=lane&3; EhG_B same with R+16.
// ---------------------------------------------------------------------------
__global__ __launch_bounds__(256) void k_elf(const float* __restrict__ enc_g,
                                             const float* __restrict__ S_g,
                                             h2* __restrict__ EhG_A,
                                             h2* __restrict__ EhG_B) {
    __shared__ float encL[32];
    __shared__ float ELf[1024];
    if (threadIdx.x < 32) encL[threadIdx.x] = enc_g[threadIdx.x];
    __syncthreads();
    for (int t = threadIdx.x; t < 1024; t += 256)
        ELf[t] = encL[t >> 5] / S_g[t] * E_SCALE;
    __syncthreads();
    {
        int t = threadIdx.x;             // 0..255 == 64 lane x 4 tt
        int lane = t >> 2, tt = t & 3;
        int R = lane >> 2, q = lane & 3;
        int i0 = q * 8 + 2 * tt;
        EhG_A[t] = h2pack(ELf[i0 * 32 + R],      ELf[(i0 + 1) * 32 + R]);
        EhG_B[t] = h2pack(ELf[i0 * 32 + R + 16], ELf[(i0 + 1) * 32 + R + 16]);
    }
}

// ---------------------------------------------------------------------------
// K4 (main): natural order; decT gather is the only indirect level. Prologue
// is now: 1KB invHL LDS copy + one 16B broadcast load per thread. LDS ~1KB,
// LB(256,8) + grid 2048 -> 8 blocks/CU, one full residency round to overlap
// the L3-latency decT gathers.
// ---------------------------------------------------------------------------
__global__ __launch_bounds__(256, 8) void k_main(const h2* __restrict__ invHLG,
                                                 const h2* __restrict__ EhG_A,
                                                 const h2* __restrict__ EhG_B,
                                                 const float* __restrict__ nd,
                                                 const int* __restrict__ nid,
                                                 const int* __restrict__ labels,
                                                 const __half* __restrict__ decT,
                                                 float* __restrict__ out) {
    __shared__ h2 invHL[256];            // [c][q][t] : c*16 + q*4 + t
    if (threadIdx.x < 64)                // 1KB coalesced copy
        reinterpret_cast<uint4*>(invHL)[threadIdx.x] =
            reinterpret_cast<const uint4*>(invHLG)[threadIdx.x];
    __syncthreads();

    int lane = threadIdx.x & 63;
    int R = lane >> 2;                   // 0..15
    int q = lane & 3;                    // i-quarter / row quad

    h2 EhA[4], EhB[4];
    {
        uint4 a = reinterpret_cast<const uint4*>(EhG_A)[lane];
        uint4 bq = reinterpret_cast<const uint4*>(EhG_B)[lane];
        EhA[0] = __builtin_bit_cast(h2, a.x);  EhA[1] = __builtin_bit_cast(h2, a.y);
        EhA[2] = __builtin_bit_cast(h2, a.z);  EhA[3] = __builtin_bit_cast(h2, a.w);
        EhB[0] = __builtin_bit_cast(h2, bq.x); EhB[1] = __builtin_bit_cast(h2, bq.y);
        EhB[2] = __builtin_bit_cast(h2, bq.z); EhB[3] = __builtin_bit_cast(h2, bq.w);
    }
    const h2 zero2 = h2pack(0.f, 0.f);
    const h2 one2 = h2pack(1.f, 1.f);

    int w = threadIdx.x >> 6;            // wave 0..3
    int start = blockIdx.x * M_CH;
    int pend = min(start + M_CH, NPAIRS);
    int pa = start + w;
    const uint4* decQ = reinterpret_cast<const uint4*>(decT);
    if (pa >= pend) return;

    auto load_ldd = [&](int pc, int* id, float* dd, int& c0, int& c1) {
        pc = min(pc, NPAIRS - 1);
        int j0 = 2 * pc, j1 = j0 + 1;
        #pragma unroll
        for (int s = 0; s < 4; ++s) {
            size_t idx = (size_t)((s >> 1) ? j1 : j0) * 32 + (s & 1) * 16 + R;
            id[s] = __builtin_nontemporal_load(&nid[idx]);
            dd[s] = __builtin_nontemporal_load(&nd[idx]);
        }
        c0 = labels[j0];
        c1 = labels[j1];
    };
    auto load_rows = [&](const int* id, uint4* r) {
        #pragma unroll
        for (int s = 0; s < 4; ++s)
            r[s] = decQ[(size_t)id[s] * 4 + q];
    };
    auto load_ih = [&](int c0, int c1, h2* ih0, h2* ih1) {
        uint4 a = *reinterpret_cast<const uint4*>(&invHL[c0 * 16 + q * 4]);
        uint4 bq = *reinterpret_cast<const uint4*>(&invHL[c1 * 16 + q * 4]);
        ih0[0] = __builtin_bit_cast(h2, a.x);  ih0[1] = __builtin_bit_cast(h2, a.y);
        ih0[2] = __builtin_bit_cast(h2, a.z);  ih0[3] = __builtin_bit_cast(h2, a.w);
        ih1[0] = __builtin_bit_cast(h2, bq.x); ih1[1] = __builtin_bit_cast(h2, bq.y);
        ih1[2] = __builtin_bit_cast(h2, bq.z); ih1[3] = __builtin_bit_cast(h2, bq.w);
    };

    // pipeline: A = compute, B = rows+ih fetched this iter, C = linear loads
    int ida[4], idb[4]; float dda[4], ddb[4];
    int ca0, ca1, cb0, cb1;
    uint4 ra[4], rb[4];
    h2 ihA0[4], ihA1[4];

    load_ldd(pa, ida, dda, ca0, ca1);
    load_ldd(pa + 4, idb, ddb, cb0, cb1);
    load_rows(ida, ra);
    load_ih(ca0, ca1, ihA0, ihA1);

    while (pa < pend) {
        load_rows(idb, rb);
        h2 ihB0[4], ihB1[4];
        load_ih(cb0, cb1, ihB0, ihB1);
        int idc[4]; float ddc[4]; int cc0, cc1;
        load_ldd(pa + 8, idc, ddc, cc0, cc1);
        __builtin_amdgcn_sched_barrier(0);

        float d20 = dda[0] * dda[0];
        float d21 = dda[1] * dda[1];
        float d22 = dda[2] * dda[2];
        float d23 = dda[3] * dda[3];
        h2 md0 = h2pack(-d20, -d20);
        h2 md1 = h2pack(-d21, -d21);
        h2 md2 = h2pack(-d22, -d22);
        h2 md3 = h2pack(-d23, -d23);

        float a0 = 0.f, a1 = 0.f, a2 = 0.f, a3 = 0.f;
        #pragma unroll
        for (int t = 0; t < 4; ++t) {
            uint dw0 = (t == 0) ? ra[0].x : (t == 1) ? ra[0].y : (t == 2) ? ra[0].z : ra[0].w;
            uint dw1 = (t == 0) ? ra[1].x : (t == 1) ? ra[1].y : (t == 2) ? ra[1].z : ra[1].w;
            uint dw2 = (t == 0) ? ra[2].x : (t == 1) ? ra[2].y : (t == 2) ? ra[2].z : ra[2].w;
            uint dw3 = (t == 0) ? ra[3].x : (t == 1) ? ra[3].y : (t == 2) ? ra[3].z : ra[3].w;
            {
                h2 wv = h2max(h2fma(md0, ihA0[t], one2), zero2);
                a0 = fdot2f(wv * EhA[t], __builtin_bit_cast(h2, dw0), a0);
            }
            {
                h2 wv = h2max(h2fma(md1, ihA0[t], one2), zero2);
                a1 = fdot2f(wv * EhB[t], __builtin_bit_cast(h2, dw1), a1);
            }
            {
                h2 wv = h2max(h2fma(md2, ihA1[t], one2), zero2);
                a2 = fdot2f(wv * EhA[t], __builtin_bit_cast(h2, dw2), a2);
            }
            {
                h2 wv = h2max(h2fma(md3, ihA1[t], one2), zero2);
                a3 = fdot2f(wv * EhB[t], __builtin_bit_cast(h2, dw3), a3);
            }
        }
        float u = a0 + a1;               // j0 partial
        float v = a2 + a3;               // j1 partial
        #pragma unroll
        for (int off = 32; off > 0; off >>= 1) {
            u += __shfl_xor(u, off);
            v += __shfl_xor(v, off);
        }
        if (lane == 0)  out[2 * pa]     = u * E_SCALE_INV;
        if (lane == 32) out[2 * pa + 1] = v * E_SCALE_INV;

        // shift pipeline
        ca0 = cb0; ca1 = cb1; cb0 = cc0; cb1 = cc1;
        #pragma unroll
        for (int s = 0; s < 4; ++s) {
            dda[s] = ddb[s]; ddb[s] = ddc[s];
            ida[s] = idb[s]; idb[s] = idc[s];
            ra[s] = rb[s];
            ihA0[s] = ihB0[s]; ihA1[s] = ihB1[s];
        }
        pa += 4;
    }
}

// ---------------------------------------------------------------------------
extern "C" void kernel_launch(void* const* d_in, const int* in_sizes, int n_in,
                              void* d_out, int out_size, void* d_ws, size_t ws_size,
                              hipStream_t stream) {
    const float* x     = (const float*)d_in[0];
    const float* enc_w = (const float*)d_in[1];
    const float* enc_b = (const float*)d_in[2];
    const float* dec   = (const float*)d_in[3];
    const float* bw_w  = (const float*)d_in[4];
    const float* bw_b  = (const float*)d_in[5];
    const float* nd    = (const float*)d_in[6];
    const int*   nid   = (const int*)d_in[7];
    const int*   labels= (const int*)d_in[8];
    float* out = (float*)d_out;

    // ws layout:
    //   [0,128)              enc (32 f)
    //   [128,4224)           S (1024 f)
    //   [4224,6272)          invFG (512 f)
    //   [6272,7296)          invHLG (256 h2)
    //   [7296,8320)          EhG_A (256 h2)
    //   [8320,9344)          EhG_B (256 h2)
    //   [532480,6932480)     decT (N*32 fp16, 6.4 MB)
    //   [6932480,11126784)   S_part (1024*1024 f, 4 MB)  [if ws permits]
    char* ws = (char*)d_ws;
    float* enc    = (float*)(ws + 0);
    float* S      = (float*)(ws + 128);
    float* invFG  = (float*)(ws + 4224);
    h2*    invHLG = (h2*)(ws + 6272);
    h2*    EhG_A  = (h2*)(ws + 7296);
    h2*    EhG_B  = (h2*)(ws + 8320);
    __half* decT  = (__half*)(ws + 532480);
    bool use_part = ws_size >= 11126784ull;
    float* S_part = use_part ? (float*)(ws + 6932480) : nullptr;

    (void)hipMemsetAsync(d_ws, 0, 4224, stream);    // enc, S
    k_prep<<<dim3(ENC_BLKS), dim3(256), 0, stream>>>(x, enc_w, enc_b, enc);
    k_tab<<<dim3(1), dim3(256), 0, stream>>>(enc, bw_w, bw_b, invFG, invHLG);
    k_S<<<dim3(S_BLKS + TR_BLKS), dim3(256), 0, stream>>>(
        invFG, nd, labels, S, S_part, dec, decT);
    if (use_part)
        k_S_reduce<<<dim3(64), dim3(1024), 0, stream>>>(S_part, S);
    k_elf<<<dim3(1), dim3(256), 0, stream>>>(enc, S, EhG_A, EhG_B);
    k_main<<<dim3(M_BLKS), dim3(256), 0, stream>>>(invHLG, EhG_A, EhG_B,
                                                   nd, nid, labels, decT, out);
}

// Round 6
// 174.745 us; speedup vs baseline: 1.4873x; 1.4873x over previous
//
#include <hip/hip_runtime.h>
#include <hip/hip_fp16.h>

#define N_PTS 100000
#define MU_F  100.0f

typedef unsigned int uint;
typedef _Float16 h2 __attribute__((ext_vector_type(2)));
typedef float f2 __attribute__((ext_vector_type(2)));

#define E_SCALE 16384.0f
#define E_SCALE_INV (1.0f / 16384.0f)

static __device__ inline h2 h2pack(float a, float b) {
    return __builtin_bit_cast(h2, __builtin_amdgcn_cvt_pkrtz(a, b));
}
static __device__ inline float fdot2f(h2 a, h2 b, float c) {
    return __builtin_amdgcn_fdot2(a, b, c, false);
}
static __device__ inline h2 h2fma(h2 a, h2 b, h2 c) {
#if __has_builtin(__builtin_elementwise_fma)
    return __builtin_elementwise_fma(a, b, c);
#else
    return a * b + c;
#endif
}
static __device__ inline h2 h2max(h2 a, h2 b) {
#if __has_builtin(__builtin_elementwise_max)
    return __builtin_elementwise_max(a, b);
#else
    h2 r;
    r.x = a.x > b.x ? a.x : b.x;
    r.y = a.y > b.y ? a.y : b.y;
    return r;
#endif
}

#define ENC_BLKS 256
#define TR_BLKS  1563            // ceil(100000/64), appended to K2's grid
#define S_BLKS   1024
#define S_PCH    98              // ceil(100000/1024) points per S-block
#define NPAIRS   (N_PTS / 2)     // 50000
#define M_BLKS   2048
#define M_CH     ((NPAIRS + M_BLKS - 1) / M_BLKS)   // 25

// ---------------------------------------------------------------------------
// K1: encode only. enc[row] = x . encW[row,:] + encB[row]
// ---------------------------------------------------------------------------
__global__ __launch_bounds__(256) void k_prep(const float* __restrict__ x,
                                              const float* __restrict__ encW,
                                              const float* __restrict__ encB,
                                              float* __restrict__ enc) {
    int b = blockIdx.x;
    int row = b & 31;
    int chunk = b >> 5;              // 0..7
    const int CH = N_PTS / 8;        // 12500
    int base = chunk * CH;
    const float4* W4 = reinterpret_cast<const float4*>(encW + (size_t)row * N_PTS + base);
    const float4* x4 = reinterpret_cast<const float4*>(x + base);
    const int nv = CH / 4;           // 3125
    float acc = 0.f;
    for (int idx = threadIdx.x; idx < nv; idx += 256) {
        float4 w = W4[idx];
        float4 xv = x4[idx];
        acc += w.x * xv.x + w.y * xv.y + w.z * xv.z + w.w * xv.w;
    }
    #pragma unroll
    for (int off = 32; off > 0; off >>= 1) acc += __shfl_down(acc, off);
    __shared__ float sred[4];
    int wid = threadIdx.x >> 6;
    if ((threadIdx.x & 63) == 0) sred[wid] = acc;
    __syncthreads();
    if (threadIdx.x == 0) {
        float s = sred[0] + sred[1] + sred[2] + sred[3];
        if (chunk == 0) s += encB[row];
        atomicAdd(enc + row, s);
    }
}

// ---------------------------------------------------------------------------
// K_tab (1 block): build invFG[512] (f32) and invHLG[256] (packed h2) ONCE.
// invF[c*32+i] = 1/(sigmoid(enc.bw_w[i*16+c]+b)*MU/60)^2
// ---------------------------------------------------------------------------
__global__ __launch_bounds__(256) void k_tab(const float* __restrict__ enc_g,
                                             const float* __restrict__ bw_w,
                                             const float* __restrict__ bw_b,
                                             float* __restrict__ invFG,
                                             h2* __restrict__ invHLG) {
    __shared__ float encL[32];
    __shared__ float invF[512];
    if (threadIdx.x < 32) encL[threadIdx.x] = enc_g[threadIdx.x];
    __syncthreads();
    for (int r = threadIdx.x; r < 512; r += 256) {
        int i = r >> 4, c = r & 15;
        const float4* wr4 = reinterpret_cast<const float4*>(bw_w + (size_t)r * 32);
        float z = bw_b[r];
        #pragma unroll
        for (int p4 = 0; p4 < 8; ++p4) {
            float4 wv = wr4[p4];
            z = fmaf(encL[4 * p4 + 0], wv.x, z);
            z = fmaf(encL[4 * p4 + 1], wv.y, z);
            z = fmaf(encL[4 * p4 + 2], wv.z, z);
            z = fmaf(encL[4 * p4 + 3], wv.w, z);
        }
        float s = 1.f / (1.f + __expf(-z));
        float wmu = s * (MU_F / 60.0f);
        float iv = 1.f / (wmu * wmu);
        invF[c * 32 + i] = iv;
        invFG[c * 32 + i] = iv;
    }
    __syncthreads();
    {
        int t = threadIdx.x;             // 0..255 == 16c x 4q x 4tt
        int c = t >> 4, q = (t >> 2) & 3, tt = t & 3;
        int i0 = q * 8 + 2 * tt;
        invHLG[t] = h2pack(fminf(invF[c * 32 + i0], 6.0e4f),
                           fminf(invF[c * 32 + i0 + 1], 6.0e4f));
    }
}

// ---------------------------------------------------------------------------
// K2: blocks [0,1024): S partials — CELL-OWNERSHIP layout (round-5 post-
//     mortem: the 32-acc/lane structure spilled; 155MB scratch writes).
//     Thread t = (ig,kk), ig=t>>5, kk=t&31 owns cells i=ig*4+r (r<4).
//     Whole block walks its 98 points together: labels[j] is a SCALAR load
//     (j uniform), nd[j*32+kk] is one 128B line/wave, one ds_read_b128 of
//     invF per point per thread. ~45 live VGPRs -> no spill at (256,4).
//     Exclusive cells -> direct S_part stores; no LDS atomics, no shuffles.
//     blocks [1024,2587): dec [32,N] f32 -> decT [N,32] fp16 transpose.
// ---------------------------------------------------------------------------
__global__ __launch_bounds__(256, 4) void k_S(const float* __restrict__ invFG,
                                              const float* __restrict__ nd,
                                              const int* __restrict__ labels,
                                              float* __restrict__ S,
                                              float* __restrict__ S_part,
                                              const float* __restrict__ dec,
                                              __half* __restrict__ decT) {
    int b = blockIdx.x;
    if (b >= S_BLKS) {
        // ----- transpose dec [32,N] f32 -> decT [N,32] fp16 (64B rows)
        __shared__ float tile[32][65];
        int j0 = (b - S_BLKS) * 64;
        int col = threadIdx.x & 63;
        int r0 = threadIdx.x >> 6;       // 0..3
        #pragma unroll
        for (int it = 0; it < 8; ++it) {
            int row = it * 4 + r0;
            int j = j0 + col;
            float v = (j < N_PTS) ? dec[(size_t)row * N_PTS + j] : 0.f;
            tile[row][col] = v;
        }
        __syncthreads();
        #pragma unroll
        for (int it = 0; it < 4; ++it) {
            int idx = it * 256 + threadIdx.x;
            int j = idx >> 4;            // 0..63
            int p = idx & 15;            // i-pair
            int jj = j0 + j;
            if (jj < N_PTS) {
                __half2 h = __halves2half2(__float2half(tile[2 * p][j]),
                                           __float2half(tile[2 * p + 1][j]));
                *reinterpret_cast<__half2*>(decT + (size_t)jj * 32 + 2 * p) = h;
            }
        }
        return;
    }

    __shared__ float invF[512];
    if (threadIdx.x < 128)               // 2KB coalesced table load
        reinterpret_cast<float4*>(invF)[threadIdx.x] =
            reinterpret_cast<const float4*>(invFG)[threadIdx.x];
    __syncthreads();

    int kk = threadIdx.x & 31;
    int ig = threadIdx.x >> 5;           // 0..7
    int start = b * S_PCH;
    int jend = min(start + S_PCH, N_PTS);

    float a0 = 0.f, a1 = 0.f, a2 = 0.f, a3 = 0.f;

    // invalid/padded points get d=1e15 -> relu(1 - 1e30*inv) == 0 exactly
    // (inv >= 0.36), so they contribute nothing.
    auto ld4 = [&](int jbase, float* d, int* cc) {
        #pragma unroll
        for (int u = 0; u < 4; ++u) {
            int j = jbase + u;
            int jc = min(j, N_PTS - 1);
            float dv = nd[(size_t)jc * 32 + kk];
            cc[u] = labels[jc];          // uniform j -> scalar load
            d[u] = (j < jend) ? dv : 1.0e15f;
        }
    };
    float dA[4], dB[4]; int cA[4], cB[4];
    ld4(start, dA, cA);
    for (int jj = start; jj < jend; jj += 4) {
        ld4(jj + 4, dB, cB);             // prefetch next batch
        #pragma unroll
        for (int u = 0; u < 4; ++u) {
            float4 iv = *reinterpret_cast<const float4*>(&invF[cA[u] * 32 + ig * 4]);
            float d2 = dA[u] * dA[u];
            a0 += fmaxf(fmaf(d2, -iv.x, 1.f), 0.f);
            a1 += fmaxf(fmaf(d2, -iv.y, 1.f), 0.f);
            a2 += fmaxf(fmaf(d2, -iv.z, 1.f), 0.f);
            a3 += fmaxf(fmaf(d2, -iv.w, 1.f), 0.f);
        }
        #pragma unroll
        for (int u = 0; u < 4; ++u) { dA[u] = dB[u]; cA[u] = cB[u]; }
    }

    int cell = (ig * 4) * 32 + kk;       // i = ig*4+r -> cell + r*32
    if (S_part) {
        float* dst = S_part + (size_t)b * 1024 + cell;
        dst[0] = a0; dst[32] = a1; dst[64] = a2; dst[96] = a3;
    } else {
        atomicAdd(&S[cell], a0);
        atomicAdd(&S[cell + 32], a1);
        atomicAdd(&S[cell + 64], a2);
        atomicAdd(&S[cell + 96], a3);
    }
}

// ---------------------------------------------------------------------------
// K3: reduce S_part (1024 x 1024) into S (pre-zeroed). grid 64 x 1024.
// ---------------------------------------------------------------------------
__global__ __launch_bounds__(1024) void k_S_reduce(const float* __restrict__ S_part,
                                                   float* __restrict__ S) {
    int g = blockIdx.x;                  // 0..63
    int t = threadIdx.x;                 // 0..1023
    float s = 0.f;
    #pragma unroll
    for (int u = 0; u < 16; ++u)
        s += S_part[(size_t)(g * 16 + u) * 1024 + t];
    atomicAdd(&S[t], s);
}

// ---------------------------------------------------------------------------
// K_elf (1 block): build pre-packed fp16 E tables ONCE.
// EhG_A[lane*4+tt] = pack(ELf[i0*32+R], ELf[(i0+1)*32+R]), i0=q*8+2tt,
// R=lane>>2, q=lane&3; EhG_B same with R+16.
// ---------------------------------------------------------------------------
__global__ __launch_bounds__(256) void k_elf(const float* __restrict__ enc_g,
                                             const float* __restrict__ S_g,
                                             h2* __restrict__ EhG_A,
                                             h2* __restrict__ EhG_B) {
    __shared__ float encL[32];
    __shared__ float ELf[1024];
    if (threadIdx.x < 32) encL[threadIdx.x] = enc_g[threadIdx.x];
    __syncthreads();
    for (int t = threadIdx.x; t < 1024; t += 256)
        ELf[t] = encL[t >> 5] / S_g[t] * E_SCALE;
    __syncthreads();
    {
        int t = threadIdx.x;             // 0..255 == 64 lane x 4 tt
        int lane = t >> 2, tt = t & 3;
        int R = lane >> 2, q = lane & 3;
        int i0 = q * 8 + 2 * tt;
        EhG_A[t] = h2pack(ELf[i0 * 32 + R],      ELf[(i0 + 1) * 32 + R]);
        EhG_B[t] = h2pack(ELf[i0 * 32 + R + 16], ELf[(i0 + 1) * 32 + R + 16]);
    }
}

// ---------------------------------------------------------------------------
// K4 (main): natural order; decT gather is the only indirect level, pipelined
// one iteration ahead. (256,4) — round-5's (256,8) cap caused spills.
// Prologue: 1KB invHL LDS copy + one 16B load per thread (tables from
// k_tab/k_elf). Grid 2048, 16 waves/CU resident to overlap L3-latency
// gathers (decT 6.4MB thrashes 4MB/XCD L2; FETCH ~109MB intrinsic).
// ---------------------------------------------------------------------------
__global__ __launch_bounds__(256, 4) void k_main(const h2* __restrict__ invHLG,
                                                 const h2* __restrict__ EhG_A,
                                                 const h2* __restrict__ EhG_B,
                                                 const float* __restrict__ nd,
                                                 const int* __restrict__ nid,
                                                 const int* __restrict__ labels,
                                                 const __half* __restrict__ decT,
                                                 float* __restrict__ out) {
    __shared__ h2 invHL[256];            // [c][q][t] : c*16 + q*4 + t
    if (threadIdx.x < 64)                // 1KB coalesced copy
        reinterpret_cast<uint4*>(invHL)[threadIdx.x] =
            reinterpret_cast<const uint4*>(invHLG)[threadIdx.x];
    __syncthreads();

    int lane = threadIdx.x & 63;
    int R = lane >> 2;                   // 0..15
    int q = lane & 3;                    // i-quarter / row quad

    h2 EhA[4], EhB[4];
    {
        uint4 a = reinterpret_cast<const uint4*>(EhG_A)[lane];
        uint4 bq = reinterpret_cast<const uint4*>(EhG_B)[lane];
        EhA[0] = __builtin_bit_cast(h2, a.x);  EhA[1] = __builtin_bit_cast(h2, a.y);
        EhA[2] = __builtin_bit_cast(h2, a.z);  EhA[3] = __builtin_bit_cast(h2, a.w);
        EhB[0] = __builtin_bit_cast(h2, bq.x); EhB[1] = __builtin_bit_cast(h2, bq.y);
        EhB[2] = __builtin_bit_cast(h2, bq.z); EhB[3] = __builtin_bit_cast(h2, bq.w);
    }
    const h2 zero2 = h2pack(0.f, 0.f);
    const h2 one2 = h2pack(1.f, 1.f);

    int w = threadIdx.x >> 6;            // wave 0..3
    int start = blockIdx.x * M_CH;
    int pend = min(start + M_CH, NPAIRS);
    int pa = start + w;
    const uint4* decQ = reinterpret_cast<const uint4*>(decT);
    if (pa >= pend) return;

    auto load_ldd = [&](int pc, int* id, float* dd, int& c0, int& c1) {
        pc = min(pc, NPAIRS - 1);
        int j0 = 2 * pc, j1 = j0 + 1;
        #pragma unroll
        for (int s = 0; s < 4; ++s) {
            size_t idx = (size_t)((s >> 1) ? j1 : j0) * 32 + (s & 1) * 16 + R;
            id[s] = __builtin_nontemporal_load(&nid[idx]);
            dd[s] = __builtin_nontemporal_load(&nd[idx]);
        }
        c0 = labels[j0];
        c1 = labels[j1];
    };
    auto load_rows = [&](const int* id, uint4* r) {
        #pragma unroll
        for (int s = 0; s < 4; ++s)
            r[s] = decQ[(size_t)id[s] * 4 + q];
    };
    auto load_ih = [&](int c0, int c1, h2* ih0, h2* ih1) {
        uint4 a = *reinterpret_cast<const uint4*>(&invHL[c0 * 16 + q * 4]);
        uint4 bq = *reinterpret_cast<const uint4*>(&invHL[c1 * 16 + q * 4]);
        ih0[0] = __builtin_bit_cast(h2, a.x);  ih0[1] = __builtin_bit_cast(h2, a.y);
        ih0[2] = __builtin_bit_cast(h2, a.z);  ih0[3] = __builtin_bit_cast(h2, a.w);
        ih1[0] = __builtin_bit_cast(h2, bq.x); ih1[1] = __builtin_bit_cast(h2, bq.y);
        ih1[2] = __builtin_bit_cast(h2, bq.z); ih1[3] = __builtin_bit_cast(h2, bq.w);
    };

    // pipeline: A = compute, B = rows+ih fetched this iter, C = linear loads
    int ida[4], idb[4]; float dda[4], ddb[4];
    int ca0, ca1, cb0, cb1;
    uint4 ra[4], rb[4];
    h2 ihA0[4], ihA1[4];

    load_ldd(pa, ida, dda, ca0, ca1);
    load_ldd(pa + 4, idb, ddb, cb0, cb1);
    load_rows(ida, ra);
    load_ih(ca0, ca1, ihA0, ihA1);

    while (pa < pend) {
        load_rows(idb, rb);
        h2 ihB0[4], ihB1[4];
        load_ih(cb0, cb1, ihB0, ihB1);
        int idc[4]; float ddc[4]; int cc0, cc1;
        load_ldd(pa + 8, idc, ddc, cc0, cc1);
        __builtin_amdgcn_sched_barrier(0);

        float d20 = dda[0] * dda[0];
        float d21 = dda[1] * dda[1];
        float d22 = dda[2] * dda[2];
        float d23 = dda[3] * dda[3];
        h2 md0 = h2pack(-d20, -d20);
        h2 md1 = h2pack(-d21, -d21);
        h2 md2 = h2pack(-d22, -d22);
        h2 md3 = h2pack(-d23, -d23);

        float a0 = 0.f, a1 = 0.f, a2 = 0.f, a3 = 0.f;
        #pragma unroll
        for (int t = 0; t < 4; ++t) {
            uint dw0 = (t == 0) ? ra[0].x : (t == 1) ? ra[0].y : (t == 2) ? ra[0].z : ra[0].w;
            uint dw1 = (t == 0) ? ra[1].x : (t == 1) ? ra[1].y : (t == 2) ? ra[1].z : ra[1].w;
            uint dw2 = (t == 0) ? ra[2].x : (t == 1) ? ra[2].y : (t == 2) ? ra[2].z : ra[2].w;
            uint dw3 = (t == 0) ? ra[3].x : (t == 1) ? ra[3].y : (t == 2) ? ra[3].z : ra[3].w;
            {
                h2 wv = h2max(h2fma(md0, ihA0[t], one2), zero2);
                a0 = fdot2f(wv * EhA[t], __builtin_bit_cast(h2, dw0), a0);
            }
            {
                h2 wv = h2max(h2fma(md1, ihA0[t], one2), zero2);
                a1 = fdot2f(wv * EhB[t], __builtin_bit_cast(h2, dw1), a1);
            }
            {
                h2 wv = h2max(h2fma(md2, ihA1[t], one2), zero2);
                a2 = fdot2f(wv * EhA[t], __builtin_bit_cast(h2, dw2), a2);
            }
            {
                h2 wv = h2max(h2fma(md3, ihA1[t], one2), zero2);
                a3 = fdot2f(wv * EhB[t], __builtin_bit_cast(h2, dw3), a3);
            }
        }
        float u = a0 + a1;               // j0 partial
        float v = a2 + a3;               // j1 partial
        #pragma unroll
        for (int off = 32; off > 0; off >>= 1) {
            u += __shfl_xor(u, off);
            v += __shfl_xor(v, off);
        }
        if (lane == 0)  out[2 * pa]     = u * E_SCALE_INV;
        if (lane == 32) out[2 * pa + 1] = v * E_SCALE_INV;

        // shift pipeline
        ca0 = cb0; ca1 = cb1; cb0 = cc0; cb1 = cc1;
        #pragma unroll
        for (int s = 0; s < 4; ++s) {
            dda[s] = ddb[s]; ddb[s] = ddc[s];
            ida[s] = idb[s]; idb[s] = idc[s];
            ra[s] = rb[s];
            ihA0[s] = ihB0[s]; ihA1[s] = ihB1[s];
        }
        pa += 4;
    }
}

// ---------------------------------------------------------------------------
extern "C" void kernel_launch(void* const* d_in, const int* in_sizes, int n_in,
                              void* d_out, int out_size, void* d_ws, size_t ws_size,
                              hipStream_t stream) {
    const float* x     = (const float*)d_in[0];
    const float* enc_w = (const float*)d_in[1];
    const float* enc_b = (const float*)d_in[2];
    const float* dec   = (const float*)d_in[3];
    const float* bw_w  = (const float*)d_in[4];
    const float* bw_b  = (const float*)d_in[5];
    const float* nd    = (const float*)d_in[6];
    const int*   nid   = (const int*)d_in[7];
    const int*   labels= (const int*)d_in[8];
    float* out = (float*)d_out;

    // ws layout:
    //   [0,128)              enc (32 f)
    //   [128,4224)           S (1024 f)
    //   [4224,6272)          invFG (512 f)
    //   [6272,7296)          invHLG (256 h2)
    //   [7296,8320)          EhG_A (256 h2)
    //   [8320,9344)          EhG_B (256 h2)
    //   [532480,6932480)     decT (N*32 fp16, 6.4 MB)
    //   [6932480,11126784)   S_part (1024*1024 f, 4 MB)  [if ws permits]
    char* ws = (char*)d_ws;
    float* enc    = (float*)(ws + 0);
    float* S      = (float*)(ws + 128);
    float* invFG  = (float*)(ws + 4224);
    h2*    invHLG = (h2*)(ws + 6272);
    h2*    EhG_A  = (h2*)(ws + 7296);
    h2*    EhG_B  = (h2*)(ws + 8320);
    __half* decT  = (__half*)(ws + 532480);
    bool use_part = ws_size >= 11126784ull;
    float* S_part = use_part ? (float*)(ws + 6932480) : nullptr;

    (void)hipMemsetAsync(d_ws, 0, 4224, stream);    // enc, S
    k_prep<<<dim3(ENC_BLKS), dim3(256), 0, stream>>>(x, enc_w, enc_b, enc);
    k_tab<<<dim3(1), dim3(256), 0, stream>>>(enc, bw_w, bw_b, invFG, invHLG);
    k_S<<<dim3(S_BLKS + TR_BLKS), dim3(256), 0, stream>>>(
        invFG, nd, labels, S, S_part, dec, decT);
    if (use_part)
        k_S_reduce<<<dim3(64), dim3(1024), 0, stream>>>(S_part, S);
    k_elf<<<dim3(1), dim3(256), 0, stream>>>(enc, S, EhG_A, EhG_B);
    k_main<<<dim3(M_BLKS), dim3(256), 0, stream>>>(invHLG, EhG_A, EhG_B,
                                                   nd, nid, labels, decT, out);
}